// Round 1
// baseline (71.942 us; speedup 1.0000x reference)
//
#include <hip/hip_runtime.h>

#define DEV static __device__ __forceinline__

typedef __bf16 bf16x8 __attribute__((ext_vector_type(8)));
typedef float  f32x16 __attribute__((ext_vector_type(16)));

// 32x32 MFMA C/D row for reg r, lane-half hi:  (verified m74/m101)
DEV int rowmap(int r, int hi) { return (r & 3) + 8 * (r >> 2) + 4 * hi; }

// byte offset into row-major [rows][128] bf16 tile (256B row stride),
// 16B-block XOR swizzle: block ^= (row&7)  [G4 / m201 pattern]
DEV int swz128(int row, int col) {
  return row * 256 + (((((col >> 3) ^ (row & 7)) << 3) | (col & 7)) << 1);
}
// byte offset into [128 d][256 k] bf16 tile (512B row stride), same swizzle
DEV int swzVT(int d, int k) {
  return d * 512 + (((((k >> 3) ^ (d & 7)) << 3) | (k & 7)) << 1);
}

DEV unsigned pack2(float lo, float hi) {
  union { __bf16 h[2]; unsigned u; } x;
  x.h[0] = (__bf16)lo; x.h[1] = (__bf16)hi;
  return x.u;
}

// Convert 8 consecutive D-layout regs (rows (r&3)+8*(r>>2)+4*hi of a 32x32
// tile, a 16-row slab) into an A/B fragment: element i <-> k = 8*(lane>>5)+i.
// Half-swap done with shfl_xor(.,32) + select ({A.lo|B.lo},{A.hi|B.hi}).
DEV bf16x8 mk_frag(float d0, float d1, float d2, float d3,
                   float d4, float d5, float d6, float d7, int lane) {
  unsigned a0 = pack2(d0, d1), a1 = pack2(d2, d3);
  unsigned b0 = pack2(d4, d5), b1 = pack2(d6, d7);
  unsigned a0s = __shfl_xor(a0, 32), a1s = __shfl_xor(a1, 32);
  unsigned b0s = __shfl_xor(b0, 32), b1s = __shfl_xor(b1, 32);
  bool lo = lane < 32;
  union { unsigned u[4]; bf16x8 v; } r;
  r.u[0] = lo ? a0  : b0s;   // k elems 0,1  (hi lanes: 8,9)
  r.u[1] = lo ? a1  : b1s;   // k elems 2,3  (hi lanes: 10,11)
  r.u[2] = lo ? a0s : b0;    // k elems 4,5  (hi lanes: 12,13)
  r.u[3] = lo ? a1s : b1;    // k elems 6,7  (hi lanes: 14,15)
  return r.v;
}

DEV f32x16 fzero() {
  f32x16 z;
  #pragma unroll
  for (int i = 0; i < 16; ++i) z[i] = 0.f;
  return z;
}

// stage a 128x128 fp32 W (row-major [e][d']) into LDS as swizzled W^T bf16
DEV void stage_w(const float* __restrict__ W, char* WT, int tid) {
  #pragma unroll
  for (int it = 0; it < 32; ++it) {
    int idx = tid + it * 512;
    int e = idx >> 7, dp = idx & 127;
    *reinterpret_cast<__bf16*>(WT + swz128(dp, e)) = (__bf16)W[idx];
  }
}

// out[32 rows, 128] = S_rows(A-frags) @ W (B-frags from swizzled W^T LDS)
DEV void proj32(const bf16x8 sf[8], const char* WT, int ml, int hi, f32x16 acc[4]) {
  #pragma unroll
  for (int t = 0; t < 4; ++t) acc[t] = fzero();
  #pragma unroll
  for (int kk = 0; kk < 8; ++kk) {
    #pragma unroll
    for (int t = 0; t < 4; ++t) {
      bf16x8 wf = *reinterpret_cast<const bf16x8*>(
          WT + swz128(32 * t + ml, 16 * kk + 8 * hi));
      acc[t] = __builtin_amdgcn_mfma_f32_32x32x16_bf16(sf[kk], wf, acc[t], 0, 0, 0);
    }
  }
}

__global__ __launch_bounds__(512, 2)
void sapd_fused(const float* __restrict__ S,
                const float* __restrict__ Wq, const float* __restrict__ bq,
                const float* __restrict__ Wk, const float* __restrict__ bk,
                const float* __restrict__ Wv, const float* __restrict__ bv,
                const float* __restrict__ Wo, const float* __restrict__ bo,
                const float* __restrict__ lg, const float* __restrict__ lb,
                float* __restrict__ out)
{
  extern __shared__ char smem[];
  char* QL = smem;            // 64 KiB: Q [256 k][128 d] bf16, swizzled
  char* VT = smem + 65536;    // 64 KiB: V^T [128 d][256 k] bf16 (K-scratch early)
  char* WT = smem + 131072;   // 32 KiB: one W^T [128][128] bf16 at a time

  const int tid  = threadIdx.x;
  const int lane = tid & 63;
  const int w    = tid >> 6;    // wave 0..7 owns rows [32w, 32w+32)
  const int ml   = lane & 31;
  const int hi   = lane >> 5;
  const int bi   = blockIdx.x;  // b*256 + i
  const size_t sbase = (size_t)bi * (256 * 128);

  // ---- S row-fragments (A operand for all three projections) ----
  bf16x8 sfrag[8];
  {
    const float* srow = S + sbase + (size_t)(32 * w + ml) * 128;
    #pragma unroll
    for (int kk = 0; kk < 8; ++kk) {
      float4 a = *reinterpret_cast<const float4*>(srow + 16 * kk + 8 * hi);
      float4 b = *reinterpret_cast<const float4*>(srow + 16 * kk + 8 * hi + 4);
      bf16x8 f;
      f[0] = (__bf16)a.x; f[1] = (__bf16)a.y; f[2] = (__bf16)a.z; f[3] = (__bf16)a.w;
      f[4] = (__bf16)b.x; f[5] = (__bf16)b.y; f[6] = (__bf16)b.z; f[7] = (__bf16)b.w;
      sfrag[kk] = f;
    }
  }

  f32x16 acc[4];

  // ---- K projection (rows j own) -> B-fragments in registers ----
  stage_w(Wk, WT, tid);
  __syncthreads();
  proj32(sfrag, WT, ml, hi, acc);
  {
    char* KS = VT + w * 8192;  // wave-private scratch [32 j][128 d] swizzled
    #pragma unroll
    for (int t = 0; t < 4; ++t) {
      float bb = bk[32 * t + ml];
      #pragma unroll
      for (int r = 0; r < 16; ++r)
        *reinterpret_cast<__bf16*>(KS + swz128(rowmap(r, hi), 32 * t + ml)) =
            (__bf16)(acc[t][r] + bb);
    }
  }
  __syncthreads();
  bf16x8 kfrag[8];
  {
    const char* KS = VT + w * 8192;
    #pragma unroll
    for (int kk = 0; kk < 8; ++kk)
      kfrag[kk] = *reinterpret_cast<const bf16x8*>(
          KS + swz128(ml, 16 * kk + 8 * hi));
  }
  __syncthreads();  // scratch reads done: VT free for real V data

  // ---- V projection (rows k own) -> VT = V^T[d][k] in LDS ----
  stage_w(Wv, WT, tid);
  __syncthreads();
  proj32(sfrag, WT, ml, hi, acc);
  #pragma unroll
  for (int t = 0; t < 4; ++t) {
    float bb = bv[32 * t + ml];
    int d = 32 * t + ml;
    #pragma unroll
    for (int p = 0; p < 8; ++p) {
      int k = 32 * w + rowmap(2 * p, hi);  // even; pair (k, k+1)
      *reinterpret_cast<unsigned*>(VT + swzVT(d, k)) =
          pack2(acc[t][2 * p] + bb, acc[t][2 * p + 1] + bb);
    }
  }
  __syncthreads();

  // ---- Q projection (rows k own) -> QL[k][d] in LDS ----
  stage_w(Wq, WT, tid);
  __syncthreads();
  proj32(sfrag, WT, ml, hi, acc);
  #pragma unroll
  for (int t = 0; t < 4; ++t) {
    float bb = bq[32 * t + ml];
    #pragma unroll
    for (int r = 0; r < 16; ++r)
      *reinterpret_cast<__bf16*>(
          QL + swz128(32 * w + rowmap(r, hi), 32 * t + ml)) =
          (__bf16)(acc[t][r] + bb);
  }
  __syncthreads();
  stage_w(Wo, WT, tid);
  __syncthreads();  // QL, VT, WT(=Wo^T) all ready

  // ---- attention: scores^T = Q·K^T (per k-tile), relu, ctx^T += V^T·P^T ----
  f32x16 ctx[4];
  #pragma unroll
  for (int m = 0; m < 4; ++m) ctx[m] = fzero();
  const float SC = 0.088388347648318447f;  // 1/sqrt(128)

  #pragma unroll 2
  for (int kt = 0; kt < 8; ++kt) {
    f32x16 sa = fzero();
    #pragma unroll
    for (int kk = 0; kk < 8; ++kk) {
      bf16x8 qf = *reinterpret_cast<const bf16x8*>(
          QL + swz128(32 * kt + ml, 16 * kk + 8 * hi));
      sa = __builtin_amdgcn_mfma_f32_32x32x16_bf16(qf, kfrag[kk], sa, 0, 0, 0);
    }
    float p[16];
    #pragma unroll
    for (int r = 0; r < 16; ++r) p[r] = fmaxf(sa[r] * SC, 0.f);
    bf16x8 pf0 = mk_frag(p[0], p[1], p[2], p[3], p[4], p[5], p[6], p[7], lane);
    bf16x8 pf1 = mk_frag(p[8], p[9], p[10], p[11], p[12], p[13], p[14], p[15], lane);
    #pragma unroll
    for (int m = 0; m < 4; ++m) {
      bf16x8 vf0 = *reinterpret_cast<const bf16x8*>(
          VT + swzVT(32 * m + ml, 32 * kt + 8 * hi));
      ctx[m] = __builtin_amdgcn_mfma_f32_32x32x16_bf16(vf0, pf0, ctx[m], 0, 0, 0);
      bf16x8 vf1 = *reinterpret_cast<const bf16x8*>(
          VT + swzVT(32 * m + ml, 32 * kt + 16 + 8 * hi));
      ctx[m] = __builtin_amdgcn_mfma_f32_32x32x16_bf16(vf1, pf1, ctx[m], 0, 0, 0);
    }
  }

  // ---- out-proj: out[j own,128] = ctx(row-frags from ctx^T regs) @ Wo ----
  bf16x8 cf[8];
  #pragma unroll
  for (int m = 0; m < 4; ++m) {
    cf[2 * m]     = mk_frag(ctx[m][0], ctx[m][1], ctx[m][2], ctx[m][3],
                            ctx[m][4], ctx[m][5], ctx[m][6], ctx[m][7], lane);
    cf[2 * m + 1] = mk_frag(ctx[m][8], ctx[m][9], ctx[m][10], ctx[m][11],
                            ctx[m][12], ctx[m][13], ctx[m][14], ctx[m][15], lane);
  }
  f32x16 oa[4];
  #pragma unroll
  for (int t = 0; t < 4; ++t) oa[t] = fzero();
  #pragma unroll
  for (int kk = 0; kk < 8; ++kk) {
    #pragma unroll
    for (int t = 0; t < 4; ++t) {
      bf16x8 wf = *reinterpret_cast<const bf16x8*>(
          WT + swz128(32 * t + ml, 16 * kk + 8 * hi));
      oa[t] = __builtin_amdgcn_mfma_f32_32x32x16_bf16(cf[kk], wf, oa[t], 0, 0, 0);
    }
  }

  // ---- epilogue: +bo, +residual(fp32), LayerNorm over d', store ----
  float gg[4], lbv[4], bov[4];
  #pragma unroll
  for (int t = 0; t < 4; ++t) {
    gg[t]  = lg[32 * t + ml];
    lbv[t] = lb[32 * t + ml];
    bov[t] = bo[32 * t + ml];
  }
  float sum[16], ssq[16];
  #pragma unroll
  for (int r = 0; r < 16; ++r) { sum[r] = 0.f; ssq[r] = 0.f; }
  #pragma unroll
  for (int t = 0; t < 4; ++t) {
    #pragma unroll
    for (int r = 0; r < 16; ++r) {
      size_t off = sbase + (size_t)(32 * w + rowmap(r, hi)) * 128 + 32 * t + ml;
      float x = oa[t][r] + bov[t] + S[off];
      oa[t][r] = x;
      sum[r] += x;
      ssq[r] += x * x;
    }
  }
  #pragma unroll
  for (int r = 0; r < 16; ++r) {
    float s_ = sum[r], q_ = ssq[r];
    #pragma unroll
    for (int m = 1; m <= 16; m <<= 1) {  // stays within 32-lane half (same j)
      s_ += __shfl_xor(s_, m);
      q_ += __shfl_xor(q_, m);
    }
    float mu = s_ * (1.f / 128.f);
    float var = q_ * (1.f / 128.f) - mu * mu;
    float rs = rsqrtf(var + 1e-5f);
    float* orow = out + sbase + (size_t)(32 * w + rowmap(r, hi)) * 128;
    #pragma unroll
    for (int t = 0; t < 4; ++t)
      orow[32 * t + ml] = (oa[t][r] - mu) * rs * gg[t] + lbv[t];
  }
}

extern "C" void kernel_launch(void* const* d_in, const int* in_sizes, int n_in,
                              void* d_out, int out_size, void* d_ws, size_t ws_size,
                              hipStream_t stream) {
  (void)in_sizes; (void)n_in; (void)d_ws; (void)ws_size; (void)out_size;
  // setup_inputs order: hidden_states(unused), structure_matrix, Wq,bq, Wk,bk,
  //                     Wv,bv, Wo,bo, ln_g, ln_b
  const float* S  = (const float*)d_in[1];
  const float* Wq = (const float*)d_in[2];
  const float* bq = (const float*)d_in[3];
  const float* Wk = (const float*)d_in[4];
  const float* bk = (const float*)d_in[5];
  const float* Wv = (const float*)d_in[6];
  const float* bv = (const float*)d_in[7];
  const float* Wo = (const float*)d_in[8];
  const float* bo = (const float*)d_in[9];
  const float* lg = (const float*)d_in[10];
  const float* lb = (const float*)d_in[11];
  float* out = (float*)d_out;

  constexpr int SMEM = 163840;  // 160 KiB dynamic LDS (gfx950 max per CU)
  (void)hipFuncSetAttribute((const void*)sapd_fused,
                            hipFuncAttributeMaxDynamicSharedMemorySize, SMEM);
  sapd_fused<<<dim3(512), dim3(512), SMEM, stream>>>(
      S, Wq, bq, Wk, bk, Wv, bv, Wo, bo, lg, lb, out);
}

// Round 2
// 69.335 us; speedup vs baseline: 1.0376x; 1.0376x over previous
//
#include <hip/hip_runtime.h>

#define DEV static __device__ __forceinline__

typedef __bf16 bf16x8 __attribute__((ext_vector_type(8)));
typedef float  f32x16 __attribute__((ext_vector_type(16)));

// 32x32 MFMA C/D row for reg r, lane-half hi (verified m74/m101)
DEV int rowmap(int r, int hi) { return (r & 3) + 8 * (r >> 2) + 4 * hi; }

// 256B-row tiles (W^T, QL, K-scratch): 16B-block XOR4 swizzle (full bank spread)
DEV int swzQ(int row, int col) {
  return row * 256 + (((((col >> 3) ^ (row & 15)) << 3) | (col & 7)) << 1);
}
// 512B-row tile (V^T [128 d][256 k]): XOR5
DEV int swzV(int d, int k) {
  return d * 512 + (((((k >> 3) ^ (d & 31)) << 3) | (k & 7)) << 1);
}

DEV unsigned pack2(float lo, float hi) {
  union { __bf16 h[2]; unsigned u; } x;
  x.h[0] = (__bf16)lo; x.h[1] = (__bf16)hi;
  return x.u;
}

// D-layout (16-row slab) -> A/B fragment; half-swap via shfl_xor(.,32)+select.
DEV bf16x8 mk_frag(float d0, float d1, float d2, float d3,
                   float d4, float d5, float d6, float d7, int lane) {
  unsigned a0 = pack2(d0, d1), a1 = pack2(d2, d3);
  unsigned b0 = pack2(d4, d5), b1 = pack2(d6, d7);
  unsigned a0s = __shfl_xor(a0, 32), a1s = __shfl_xor(a1, 32);
  unsigned b0s = __shfl_xor(b0, 32), b1s = __shfl_xor(b1, 32);
  bool lo = lane < 32;
  union { unsigned u[4]; bf16x8 v; } r;
  r.u[0] = lo ? a0  : b0s;
  r.u[1] = lo ? a1  : b1s;
  r.u[2] = lo ? a0s : b0;
  r.u[3] = lo ? a1s : b1;
  return r.v;
}

DEV f32x16 fzero() {
  f32x16 z;
  #pragma unroll
  for (int i = 0; i < 16; ++i) z[i] = 0.f;
  return z;
}

// linear global->LDS copy (pre-swizzled bf16 W^T in d_ws), conflict-free
DEV void copy_lds(char* dst, const char* src, int bytes, int tid) {
  for (int off = tid * 16; off < bytes; off += 512 * 16)
    *reinterpret_cast<int4*>(dst + off) = *reinterpret_cast<const int4*>(src + off);
}

// fallback: stage fp32 W (row-major [e][d']) into LDS as swizzled W^T bf16
DEV void stage_w32(const float* __restrict__ W, char* dst, int tid) {
  #pragma unroll
  for (int it = 0; it < 32; ++it) {
    int idx = tid + it * 512;
    int e = idx >> 7, dp = idx & 127;
    *reinterpret_cast<__bf16*>(dst + swzQ(dp, e)) = (__bf16)W[idx];
  }
}

// out[32 rows, 128] = S_rows(A-frags) @ W (B-frags from swizzled W^T tile)
DEV void proj32(const bf16x8 sf[8], const char* Wt, int ml, int hi, f32x16 acc[4]) {
  #pragma unroll
  for (int t = 0; t < 4; ++t) acc[t] = fzero();
  #pragma unroll
  for (int kk = 0; kk < 8; ++kk) {
    #pragma unroll
    for (int t = 0; t < 4; ++t) {
      bf16x8 wf = *reinterpret_cast<const bf16x8*>(
          Wt + swzQ(32 * t + ml, 16 * kk + 8 * hi));
      acc[t] = __builtin_amdgcn_mfma_f32_32x32x16_bf16(sf[kk], wf, acc[t], 0, 0, 0);
    }
  }
}

// prep: W fp32 [e][d'] -> bf16 W^T swizzled, packed [Wk|Wq|Wv|Wo] in d_ws
__global__ void prep_wt(const float* __restrict__ Wk, const float* __restrict__ Wq,
                        const float* __restrict__ Wv, const float* __restrict__ Wo,
                        __bf16* __restrict__ wt) {
  int idx = blockIdx.x * 256 + threadIdx.x;   // 0..65535
  const float* W[4] = {Wk, Wq, Wv, Wo};
  int m = idx >> 14, rem = idx & 16383;
  int e = rem >> 7, dp = rem & 127;           // read W[e][dp], coalesced in dp
  wt[m * 16384 + (swzQ(dp, e) >> 1)] = (__bf16)W[m][rem];
}

template<bool WS>
__global__ __launch_bounds__(512, 2)
void sapd_fused(const float* __restrict__ S,
                const float* __restrict__ bq, const float* __restrict__ bk,
                const float* __restrict__ bv, const float* __restrict__ bo,
                const float* __restrict__ Wq, const float* __restrict__ Wk,
                const float* __restrict__ Wv, const float* __restrict__ Wo,
                const float* __restrict__ lg, const float* __restrict__ lb,
                const __bf16* __restrict__ wt,
                float* __restrict__ out)
{
  extern __shared__ char smem[];
  char* QL = smem;           // 64K: per-wave K-scratch -> Q [256][128]; Wo after loop
  char* VT = smem + 65536;   // 64K: Wk|Wq stage -> Wv stage -> V^T [128][256]

  const int tid  = threadIdx.x;
  const int lane = tid & 63;
  const int w    = tid >> 6;    // wave 0..7 owns rows [32w, 32w+32)
  const int ml   = lane & 31;
  const int hi   = lane >> 5;
  const size_t sbase = (size_t)blockIdx.x * (256 * 128);
  const char* wsc = (const char*)wt;

  // ---- S row-fragments (A operand for all three projections) ----
  bf16x8 sfrag[8];
  {
    const float* srow = S + sbase + (size_t)(32 * w + ml) * 128;
    #pragma unroll
    for (int kk = 0; kk < 8; ++kk) {
      float4 a = *reinterpret_cast<const float4*>(srow + 16 * kk + 8 * hi);
      float4 b = *reinterpret_cast<const float4*>(srow + 16 * kk + 8 * hi + 4);
      bf16x8 f;
      f[0] = (__bf16)a.x; f[1] = (__bf16)a.y; f[2] = (__bf16)a.z; f[3] = (__bf16)a.w;
      f[4] = (__bf16)b.x; f[5] = (__bf16)b.y; f[6] = (__bf16)b.z; f[7] = (__bf16)b.w;
      sfrag[kk] = f;
    }
  }

  // ---- stage Wk (VT+0) and Wq (VT+32K) ----
  if (WS) {
    copy_lds(VT, wsc, 65536, tid);
  } else {
    stage_w32(Wk, VT, tid);
    stage_w32(Wq, VT + 32768, tid);
  }
  __syncthreads();  // #1: W tiles visible

  f32x16 acc[4];
  char* KS = QL + w * 8192;  // wave-private: K-scratch now, Q rows [32w..) later

  // ---- K projection -> wave-private scratch -> kfrag (B-frags, rows j own) ----
  proj32(sfrag, VT, ml, hi, acc);
  #pragma unroll
  for (int t = 0; t < 4; ++t) {
    float bb = bk[32 * t + ml];
    #pragma unroll
    for (int r = 0; r < 16; ++r)
      *reinterpret_cast<__bf16*>(KS + swzQ(rowmap(r, hi), 32 * t + ml)) =
          (__bf16)(acc[t][r] + bb);
  }
  bf16x8 kfrag[8];
  #pragma unroll
  for (int kk = 0; kk < 8; ++kk)
    kfrag[kk] = *reinterpret_cast<const bf16x8*>(KS + swzQ(ml, 16 * kk + 8 * hi));

  // ---- Q projection -> same region (scratch dead, same-wave ordering) ----
  proj32(sfrag, VT + 32768, ml, hi, acc);
  #pragma unroll
  for (int t = 0; t < 4; ++t) {
    float bb = bq[32 * t + ml];
    #pragma unroll
    for (int r = 0; r < 16; ++r)
      *reinterpret_cast<__bf16*>(KS + swzQ(rowmap(r, hi), 32 * t + ml)) =
          (__bf16)(acc[t][r] + bb);
  }
  __syncthreads();  // #2: all waves done reading Wk/Wq

  // ---- stage Wv (VT+0) ----
  if (WS) copy_lds(VT, wsc + 65536, 32768, tid);
  else    stage_w32(Wv, VT, tid);
  __syncthreads();  // #3: Wv visible

  // ---- V projection -> V^T [d][k] over the staging region ----
  proj32(sfrag, VT, ml, hi, acc);
  __syncthreads();  // #4: all waves done reading Wv
  #pragma unroll
  for (int t = 0; t < 4; ++t) {
    float bb = bv[32 * t + ml];
    int d = 32 * t + ml;
    #pragma unroll
    for (int p = 0; p < 8; ++p) {
      int k = 32 * w + rowmap(2 * p, hi);  // even; pair (k, k+1)
      *reinterpret_cast<unsigned*>(VT + swzV(d, k)) =
          pack2(acc[t][2 * p] + bb, acc[t][2 * p + 1] + bb);
    }
  }
  __syncthreads();  // #5: QL (Q) + VT (V^T) ready

  // ---- attention: scores^T per k-tile, relu, ctx^T += V^T·P^T ----
  f32x16 ctx[4];
  #pragma unroll
  for (int m = 0; m < 4; ++m) ctx[m] = fzero();
  const float SC = 0.088388347648318447f;  // 1/sqrt(128)

  #pragma unroll 2
  for (int kt = 0; kt < 8; ++kt) {
    f32x16 sa = fzero();
    #pragma unroll
    for (int kk = 0; kk < 8; ++kk) {
      bf16x8 qf = *reinterpret_cast<const bf16x8*>(
          QL + swzQ(32 * kt + ml, 16 * kk + 8 * hi));
      sa = __builtin_amdgcn_mfma_f32_32x32x16_bf16(qf, kfrag[kk], sa, 0, 0, 0);
    }
    float p[16];
    #pragma unroll
    for (int r = 0; r < 16; ++r) p[r] = fmaxf(sa[r] * SC, 0.f);
    bf16x8 pf0 = mk_frag(p[0], p[1], p[2], p[3], p[4], p[5], p[6], p[7], lane);
    bf16x8 pf1 = mk_frag(p[8], p[9], p[10], p[11], p[12], p[13], p[14], p[15], lane);
    #pragma unroll
    for (int m = 0; m < 4; ++m) {
      bf16x8 vf0 = *reinterpret_cast<const bf16x8*>(
          VT + swzV(32 * m + ml, 32 * kt + 8 * hi));
      ctx[m] = __builtin_amdgcn_mfma_f32_32x32x16_bf16(vf0, pf0, ctx[m], 0, 0, 0);
      bf16x8 vf1 = *reinterpret_cast<const bf16x8*>(
          VT + swzV(32 * m + ml, 32 * kt + 16 + 8 * hi));
      ctx[m] = __builtin_amdgcn_mfma_f32_32x32x16_bf16(vf1, pf1, ctx[m], 0, 0, 0);
    }
  }

  // ---- ctx^T regs -> A-frags; stage Wo into QL (QL dead after loop) ----
  bf16x8 cf[8];
  #pragma unroll
  for (int m = 0; m < 4; ++m) {
    cf[2 * m]     = mk_frag(ctx[m][0], ctx[m][1], ctx[m][2], ctx[m][3],
                            ctx[m][4], ctx[m][5], ctx[m][6], ctx[m][7], lane);
    cf[2 * m + 1] = mk_frag(ctx[m][8], ctx[m][9], ctx[m][10], ctx[m][11],
                            ctx[m][12], ctx[m][13], ctx[m][14], ctx[m][15], lane);
  }
  __syncthreads();  // #6: everyone done reading QL
  if (WS) copy_lds(QL, wsc + 98304, 32768, tid);
  else    stage_w32(Wo, QL, tid);
  __syncthreads();  // #7: Wo visible

  // ---- out-proj ----
  f32x16 oa[4];
  #pragma unroll
  for (int t = 0; t < 4; ++t) oa[t] = fzero();
  #pragma unroll
  for (int kk = 0; kk < 8; ++kk) {
    #pragma unroll
    for (int t = 0; t < 4; ++t) {
      bf16x8 wf = *reinterpret_cast<const bf16x8*>(
          QL + swzQ(32 * t + ml, 16 * kk + 8 * hi));
      oa[t] = __builtin_amdgcn_mfma_f32_32x32x16_bf16(cf[kk], wf, oa[t], 0, 0, 0);
    }
  }

  // ---- epilogue: +bo, +residual(fp32), LayerNorm, store ----
  float gg[4], lbv[4], bov[4];
  #pragma unroll
  for (int t = 0; t < 4; ++t) {
    gg[t]  = lg[32 * t + ml];
    lbv[t] = lb[32 * t + ml];
    bov[t] = bo[32 * t + ml];
  }
  float sum[16], ssq[16];
  #pragma unroll
  for (int r = 0; r < 16; ++r) { sum[r] = 0.f; ssq[r] = 0.f; }
  #pragma unroll
  for (int t = 0; t < 4; ++t) {
    #pragma unroll
    for (int r = 0; r < 16; ++r) {
      size_t off = sbase + (size_t)(32 * w + rowmap(r, hi)) * 128 + 32 * t + ml;
      float x = oa[t][r] + bov[t] + S[off];
      oa[t][r] = x;
      sum[r] += x;
      ssq[r] += x * x;
    }
  }
  #pragma unroll
  for (int r = 0; r < 16; ++r) {
    float s_ = sum[r], q_ = ssq[r];
    #pragma unroll
    for (int m = 1; m <= 16; m <<= 1) {
      s_ += __shfl_xor(s_, m);
      q_ += __shfl_xor(q_, m);
    }
    float mu = s_ * (1.f / 128.f);
    float var = q_ * (1.f / 128.f) - mu * mu;
    float rs = rsqrtf(var + 1e-5f);
    float* orow = out + sbase + (size_t)(32 * w + rowmap(r, hi)) * 128;
    #pragma unroll
    for (int t = 0; t < 4; ++t)
      orow[32 * t + ml] = (oa[t][r] - mu) * rs * gg[t] + lbv[t];
  }
}

extern "C" void kernel_launch(void* const* d_in, const int* in_sizes, int n_in,
                              void* d_out, int out_size, void* d_ws, size_t ws_size,
                              hipStream_t stream) {
  (void)in_sizes; (void)n_in; (void)out_size;
  const float* S  = (const float*)d_in[1];
  const float* Wq = (const float*)d_in[2];
  const float* bq = (const float*)d_in[3];
  const float* Wk = (const float*)d_in[4];
  const float* bk = (const float*)d_in[5];
  const float* Wv = (const float*)d_in[6];
  const float* bv = (const float*)d_in[7];
  const float* Wo = (const float*)d_in[8];
  const float* bo = (const float*)d_in[9];
  const float* lg = (const float*)d_in[10];
  const float* lb = (const float*)d_in[11];
  float* out = (float*)d_out;

  constexpr int SMEM = 131072;  // 128 KiB dynamic LDS -> 1 block/CU (LDS-capped)
  bool use_ws = (d_ws != nullptr) && (ws_size >= 131072);
  if (use_ws) {
    prep_wt<<<dim3(256), dim3(256), 0, stream>>>(Wk, Wq, Wv, Wo, (__bf16*)d_ws);
    (void)hipFuncSetAttribute(reinterpret_cast<const void*>(&sapd_fused<true>),
                              hipFuncAttributeMaxDynamicSharedMemorySize, SMEM);
    sapd_fused<true><<<dim3(512), dim3(512), SMEM, stream>>>(
        S, bq, bk, bv, bo, Wq, Wk, Wv, Wo, lg, lb, (const __bf16*)d_ws, out);
  } else {
    (void)hipFuncSetAttribute(reinterpret_cast<const void*>(&sapd_fused<false>),
                              hipFuncAttributeMaxDynamicSharedMemorySize, SMEM);
    sapd_fused<false><<<dim3(512), dim3(512), SMEM, stream>>>(
        S, bq, bk, bv, bo, Wq, Wk, Wv, Wo, lg, lb, nullptr, out);
  }
}